// Round 4
// baseline (35.983 us; speedup 1.0000x reference)
//
#include <hip/hip_runtime.h>
#include <hip/hip_bf16.h>
#include <math.h>

// Problem constants: B=16, C=64, H=W=64, M=4096
#define KS 16
#define CHUNK 256
#define PART_STRIDE 4224   // 4096 S + 64 rsum + 1 T-partial + pad

typedef __attribute__((ext_vector_type(8))) short short8;
typedef __attribute__((ext_vector_type(4))) float floatx4;

__device__ __forceinline__ unsigned short f2bf(float f) {
    __hip_bfloat16 h = __float2bfloat16(f);
    return *reinterpret_cast<unsigned short*>(&h);
}
__device__ __forceinline__ float bf2f(unsigned short h) {
    return __uint_as_float(((unsigned int)h) << 16);
}
// Halfword base of element (r, k=8*kb) in the swizzled fragment layout.
__device__ __forceinline__ int HW(int r, int kb) {
    return ((kb << 6) + (r ^ (kb & 15))) << 3;
}
__device__ __forceinline__ floatx4 mfma_bf16(short8 a, short8 b, floatx4 c) {
    return __builtin_amdgcn_mfma_f32_16x16x32_bf16(a, b, c, 0, 0, 0);
}

// ---------------------------------------------------------------------------
// K1: per-(batch,chunk) partial Gram via MFMA + partial rowsums + partial
// T = sum_m (colsum_m)^2  (for normA without a full-matrix reduction).
// ---------------------------------------------------------------------------
__global__ __launch_bounds__(256) void cov_partial_kernel(const float* __restrict__ x,
                                                          float* __restrict__ ws) {
    __shared__ __align__(16) unsigned short xh[64 * CHUNK];
    __shared__ __align__(16) unsigned short xl[64 * CHUNK];
    __shared__ float rs_part[4][64];
    __shared__ float csp[4][256];
    __shared__ float red[256];
    int blk = blockIdx.x, b = blk >> 4, ks = blk & 15;
    int tid = threadIdx.x, lane = tid & 63, wv = tid >> 6;
    const float* xb = x + ((size_t)b * 64) * 4096 + ks * CHUNK;

    int kbw = lane >> 1, wsub = (lane & 1) << 2;
    float cs0 = 0.f, cs1 = 0.f, cs2 = 0.f, cs3 = 0.f;
    #pragma unroll
    for (int r = 0; r < 16; ++r) {
        int c = wv * 16 + r;
        float4 v = *reinterpret_cast<const float4*>(xb + (size_t)c * 4096 + lane * 4);
        cs0 += v.x; cs1 += v.y; cs2 += v.z; cs3 += v.w;
        float vv[4] = {v.x, v.y, v.z, v.w};
        unsigned short hs[4], ls[4];
        #pragma unroll
        for (int q = 0; q < 4; ++q) {
            hs[q] = f2bf(vv[q]);
            ls[q] = f2bf(vv[q] - bf2f(hs[q]));
        }
        int idx = HW(c, kbw) + wsub;
        uint2 u;
        u.x = hs[0] | ((unsigned)hs[1] << 16); u.y = hs[2] | ((unsigned)hs[3] << 16);
        *reinterpret_cast<uint2*>(&xh[idx]) = u;
        u.x = ls[0] | ((unsigned)ls[1] << 16); u.y = ls[2] | ((unsigned)ls[3] << 16);
        *reinterpret_cast<uint2*>(&xl[idx]) = u;
    }
    *reinterpret_cast<float4*>(&csp[wv][lane * 4]) = make_float4(cs0, cs1, cs2, cs3);
    __syncthreads();

    float cm = csp[0][tid] + csp[1][tid] + csp[2][tid] + csp[3][tid];  // colsum of m=tid

    int g = lane >> 4, rh = lane & 15;
    int ta0 = (wv >> 1) << 1, tc0 = (wv & 1) << 1;
    floatx4 acc[2][2];
    #pragma unroll
    for (int a = 0; a < 2; ++a)
        #pragma unroll
        for (int c = 0; c < 2; ++c)
            acc[a][c] = (floatx4){0.f, 0.f, 0.f, 0.f};

    #pragma unroll
    for (int ks_ = 0; ks_ < 8; ++ks_) {
        int kb = ks_ * 4 + g;
        short8 ah[2], al[2], bh[2], bl[2];
        #pragma unroll
        for (int a = 0; a < 2; ++a) {
            int o = HW(16 * (ta0 + a) + rh, kb);
            ah[a] = *reinterpret_cast<const short8*>(&xh[o]);
            al[a] = *reinterpret_cast<const short8*>(&xl[o]);
        }
        #pragma unroll
        for (int c = 0; c < 2; ++c) {
            int o = HW(16 * (tc0 + c) + rh, kb);
            bh[c] = *reinterpret_cast<const short8*>(&xh[o]);
            bl[c] = *reinterpret_cast<const short8*>(&xl[o]);
        }
        #pragma unroll
        for (int a = 0; a < 2; ++a)
            #pragma unroll
            for (int c = 0; c < 2; ++c) {
                acc[a][c] = mfma_bf16(ah[a], bh[c], acc[a][c]);
                acc[a][c] = mfma_bf16(ah[a], bl[c], acc[a][c]);
                acc[a][c] = mfma_bf16(al[a], bh[c], acc[a][c]);
            }
    }

    float* outp = ws + (size_t)blk * PART_STRIDE;
    #pragma unroll
    for (int a = 0; a < 2; ++a)
        #pragma unroll
        for (int c = 0; c < 2; ++c) {
            int j = 16 * (tc0 + c) + rh;
            int i0 = 16 * (ta0 + a) + 4 * g;
            *reinterpret_cast<float4*>(&outp[j * 64 + i0]) =
                make_float4(acc[a][c][0], acc[a][c][1], acc[a][c][2], acc[a][c][3]);
        }

    {   // partial row sums from staged planes (hi+lo ~ fp32)
        float s = 0.f;
        #pragma unroll
        for (int m = 0; m < 8; ++m) {
            int o = HW(lane, wv * 8 + m);
            short8 vh = *reinterpret_cast<const short8*>(&xh[o]);
            short8 vl = *reinterpret_cast<const short8*>(&xl[o]);
            #pragma unroll
            for (int e = 0; e < 8; ++e)
                s += bf2f((unsigned short)vh[e]) + bf2f((unsigned short)vl[e]);
        }
        rs_part[wv][lane] = s;
    }
    red[tid] = cm * cm;
    __syncthreads();
    for (int st = 128; st > 0; st >>= 1) {
        if (tid < st) red[tid] += red[tid + st];
        __syncthreads();
    }
    if (tid < 64)
        outp[4096 + tid] = rs_part[0][tid] + rs_part[1][tid] + rs_part[2][tid] + rs_part[3][tid];
    if (tid == 0) outp[4160] = red[0];
}

// ---------------------------------------------------------------------------
// K1b: full-chip reduce of split-K partials -> cov -> normA -> A,Z0 bf16
// hi/lo planes in fragment layout, written to global. 64 blocks (4/batch).
// ---------------------------------------------------------------------------
__global__ __launch_bounds__(256) void reduce_convert_kernel(const float* __restrict__ ws,
                                                             unsigned short* __restrict__ planesG,
                                                             float* __restrict__ normAG) {
    __shared__ float rsum[64];
    __shared__ float Tsh, normA_sh;
    int blk = blockIdx.x, b = blk >> 2, q = blk & 3;
    int tid = threadIdx.x;
    const float* base = ws + (size_t)b * KS * PART_STRIDE;
    const float invM = 1.0f / 4096.0f;

    if (tid < 64) {
        float s = 0.f;
        for (int k = 0; k < KS; ++k) s += base[k * PART_STRIDE + 4096 + tid];
        rsum[tid] = s;
    } else if (tid == 64) {
        float t = 0.f;
        for (int k = 0; k < KS; ++k) t += base[k * PART_STRIDE + 4160];
        Tsh = t;
    }
    __syncthreads();
    if (tid == 0) {
        float sr = 0.f;
        for (int i = 0; i < 64; ++i) sr += rsum[i];
        float nA = (Tsh - sr * sr * invM) * invM;   // sum_ij cov
        normA_sh = nA;
        if (q == 0) normAG[b] = nA;
    }
    __syncthreads();
    const float invNA = 1.0f / normA_sh;

    int E = q * 1024 + tid * 4;          // this thread's 4 elements
    int i = E >> 6, j0 = E & 63;
    floatx4 s4 = (floatx4){0.f, 0.f, 0.f, 0.f};
    for (int k = 0; k < KS; ++k)
        s4 += *reinterpret_cast<const floatx4*>(base + k * PART_STRIDE + E);
    float mui = rsum[i] * invM;
    unsigned short ah[4], al_[4], zh[4], zl[4];
    #pragma unroll
    for (int e = 0; e < 4; ++e) {
        float cv = s4[e] * invM - mui * (rsum[j0 + e] * invM);
        float a = cv * invNA;
        float z = 0.5f * (((i == j0 + e) ? 3.0f : 0.0f) - a);
        unsigned short h = f2bf(a);
        ah[e] = h; al_[e] = f2bf(a - bf2f(h));
        h = f2bf(z);
        zh[e] = h; zl[e] = f2bf(z - bf2f(h));
    }
    int kb = j0 >> 3, sub = j0 & 7;
    int idx = HW(i, kb) + sub;
    unsigned short* pb = planesG + (size_t)b * 4 * 4096;  // order: A_hi, A_lo, Z_hi, Z_lo
    uint2 u;
    u.x = ah[0] | ((unsigned)ah[1] << 16); u.y = ah[2] | ((unsigned)ah[3] << 16);
    *reinterpret_cast<uint2*>(&pb[0 * 4096 + idx]) = u;
    u.x = al_[0] | ((unsigned)al_[1] << 16); u.y = al_[2] | ((unsigned)al_[3] << 16);
    *reinterpret_cast<uint2*>(&pb[1 * 4096 + idx]) = u;
    u.x = zh[0] | ((unsigned)zh[1] << 16); u.y = zh[2] | ((unsigned)zh[3] << 16);
    *reinterpret_cast<uint2*>(&pb[2 * 4096 + idx]) = u;
    u.x = zl[0] | ((unsigned)zl[1] << 16); u.y = zl[2] | ((unsigned)zl[3] << 16);
    *reinterpret_cast<uint2*>(&pb[3 * 4096 + idx]) = u;
}

// ---------------------------------------------------------------------------
// K2 pass helpers. 16 waves. Stored matrices are transposed products (valid:
// all NS iterates are symmetric polynomials in A, so they commute).
// ---------------------------------------------------------------------------
template <int MODE>   // 0: D = 0.5*(3I - P)   1: D = P
__device__ __forceinline__ void pass_single(const unsigned short (*U)[4096],
                                            const unsigned short (*V)[4096],
                                            unsigned short (*D)[4096], int tid) {
    int lane = tid & 63, wv = tid >> 6;
    int g = lane >> 4, rh = lane & 15;
    int ta = wv & 3, tc = wv >> 2;
    floatx4 acc = (floatx4){0.f, 0.f, 0.f, 0.f};
    #pragma unroll
    for (int ks_ = 0; ks_ < 2; ++ks_) {
        int kb = ks_ * 4 + g;
        int ao = HW(16 * ta + rh, kb);
        int bo = HW(16 * tc + rh, kb);
        short8 auh = *reinterpret_cast<const short8*>(&U[0][ao]);
        short8 aul = *reinterpret_cast<const short8*>(&U[1][ao]);
        short8 bvh = *reinterpret_cast<const short8*>(&V[0][bo]);
        short8 bvl = *reinterpret_cast<const short8*>(&V[1][bo]);
        acc = mfma_bf16(auh, bvh, acc);
        acc = mfma_bf16(auh, bvl, acc);
        acc = mfma_bf16(aul, bvh, acc);
    }
    int j = 16 * tc + rh;
    int kbi = 2 * ta + (g >> 1), sub = (g & 1) << 2;
    unsigned short hs[4], ls[4];
    #pragma unroll
    for (int qq = 0; qq < 4; ++qq) {
        int i = 16 * ta + 4 * g + qq;
        float v = acc[qq];
        if (MODE == 0) v = 0.5f * ((i == j ? 3.0f : 0.0f) - v);
        hs[qq] = f2bf(v);
        ls[qq] = f2bf(v - bf2f(hs[qq]));
    }
    int idx = HW(j, kbi) + sub;
    uint2 u;
    u.x = hs[0] | ((unsigned)hs[1] << 16); u.y = hs[2] | ((unsigned)hs[3] << 16);
    *reinterpret_cast<uint2*>(&D[0][idx]) = u;
    u.x = ls[0] | ((unsigned)ls[1] << 16); u.y = ls[2] | ((unsigned)ls[3] << 16);
    *reinterpret_cast<uint2*>(&D[1][idx]) = u;
    __syncthreads();
}

// Fused dual pass: waves 0-7 compute DY = Y@W, waves 8-15 compute DZ = W@Z.
__device__ __forceinline__ void pass_fused(const unsigned short (*Y)[4096],
                                           const unsigned short (*W)[4096],
                                           const unsigned short (*Z)[4096],
                                           unsigned short (*DY)[4096],
                                           unsigned short (*DZ)[4096], int tid) {
    int lane = tid & 63, wv = tid >> 6;
    int g = lane >> 4, rh = lane & 15;
    const unsigned short (*U)[4096] = (wv < 8) ? Y : W;
    const unsigned short (*V)[4096] = (wv < 8) ? W : Z;
    unsigned short (*D)[4096] = (wv < 8) ? DY : DZ;
    int w8 = wv & 7;
    int ta0 = (w8 >> 2) << 1, tc = w8 & 3;
    floatx4 acc[2] = {(floatx4){0.f,0.f,0.f,0.f}, (floatx4){0.f,0.f,0.f,0.f}};
    #pragma unroll
    for (int ks_ = 0; ks_ < 2; ++ks_) {
        int kb = ks_ * 4 + g;
        int bo = HW(16 * tc + rh, kb);
        short8 bvh = *reinterpret_cast<const short8*>(&V[0][bo]);
        short8 bvl = *reinterpret_cast<const short8*>(&V[1][bo]);
        #pragma unroll
        for (int a = 0; a < 2; ++a) {
            int ao = HW(16 * (ta0 + a) + rh, kb);
            short8 auh = *reinterpret_cast<const short8*>(&U[0][ao]);
            short8 aul = *reinterpret_cast<const short8*>(&U[1][ao]);
            acc[a] = mfma_bf16(auh, bvh, acc[a]);
            acc[a] = mfma_bf16(auh, bvl, acc[a]);
            acc[a] = mfma_bf16(aul, bvh, acc[a]);
        }
    }
    int j = 16 * tc + rh;
    #pragma unroll
    for (int a = 0; a < 2; ++a) {
        int ta = ta0 + a;
        int kbi = 2 * ta + (g >> 1), sub = (g & 1) << 2;
        unsigned short hs[4], ls[4];
        #pragma unroll
        for (int qq = 0; qq < 4; ++qq) {
            float v = acc[a][qq];
            hs[qq] = f2bf(v);
            ls[qq] = f2bf(v - bf2f(hs[qq]));
        }
        int idx = HW(j, kbi) + sub;
        uint2 u;
        u.x = hs[0] | ((unsigned)hs[1] << 16); u.y = hs[2] | ((unsigned)hs[3] << 16);
        *reinterpret_cast<uint2*>(&D[0][idx]) = u;
        u.x = ls[0] | ((unsigned)ls[1] << 16); u.y = ls[2] | ((unsigned)ls[3] << 16);
        *reinterpret_cast<uint2*>(&D[1][idx]) = u;
    }
    __syncthreads();
}

__device__ __forceinline__ void colsum_stage(const unsigned short (*M)[4096],
                                             float* dst, float (*part)[64], int tid) {
    int ii = tid & 63, grp = (tid >> 6) & 7;
    if (tid < 512) {
        int o = HW(ii, grp);
        short8 vh = *reinterpret_cast<const short8*>(&M[0][o]);
        short8 vl = *reinterpret_cast<const short8*>(&M[1][o]);
        float s = 0.f;
        #pragma unroll
        for (int e = 0; e < 8; ++e)
            s += bf2f((unsigned short)vh[e]) + bf2f((unsigned short)vl[e]);
        part[grp][ii] = s;
    }
    __syncthreads();
    if (tid < 64) {
        float s = 0.f;
        #pragma unroll
        for (int q = 0; q < 8; ++q) s += part[q][tid];
        dst[tid] = s;
    }
    __syncthreads();
}

__device__ __forceinline__ void matvec_stage(const unsigned short (*M)[4096],
                                             const float* __restrict__ src,
                                             float* dst, float (*part)[64], int tid) {
    int ii = tid & 63, grp = (tid >> 6) & 7;
    if (tid < 512) {
        int o = HW(ii, grp);
        short8 vh = *reinterpret_cast<const short8*>(&M[0][o]);
        short8 vl = *reinterpret_cast<const short8*>(&M[1][o]);
        float s = 0.f;
        #pragma unroll
        for (int e = 0; e < 8; ++e)
            s += (bf2f((unsigned short)vh[e]) + bf2f((unsigned short)vl[e])) * src[grp * 8 + e];
        part[grp][ii] = s;
    }
    __syncthreads();
    if (tid < 64) {
        float s = 0.f;
        #pragma unroll
        for (int q = 0; q < 8; ++q) s += part[q][tid];
        dst[tid] = s;
    }
    __syncthreads();
}

// ---------------------------------------------------------------------------
// K2: one block (1024 thr) per batch. Load pre-converted A,Z0 planes ->
// 7 MFMA passes -> matvec epilogue -> conv chain.
// ---------------------------------------------------------------------------
__global__ __launch_bounds__(1024) void ns_kernel(const unsigned short* __restrict__ planesG,
                                                  const float* __restrict__ normAG,
                                                  const float* __restrict__ w1,
                                                  const float* __restrict__ b1,
                                                  const float* __restrict__ w2,
                                                  const float* __restrict__ b2,
                                                  float* __restrict__ s_out) {
    __shared__ __align__(16) unsigned short planes[5][2][4096];
    __shared__ float w1t[64 * 65];
    __shared__ float w2t[64 * 65];
    __shared__ float part[8][64];
    __shared__ float uvec[64], avec[64], pvec[64], wvec[64], ych[64], hid[64];
    __shared__ float normA_sh;
    int b = blockIdx.x, tid = threadIdx.x;

    {   // stage A,Z0 hi/lo planes (32KB, linear)
        const uint4* src = reinterpret_cast<const uint4*>(planesG + (size_t)b * 4 * 4096);
        uint4* dst = reinterpret_cast<uint4*>(&planes[0][0][0]);
        dst[tid] = src[tid];
        dst[tid + 1024] = src[tid + 1024];
    }
    {   // conv center taps w[o][i][1][1] -> [i][o]
        int o = tid & 63, g8 = tid >> 6;
        #pragma unroll
        for (int q = 0; q < 4; ++q) {
            int i = g8 * 4 + q;
            w1t[i * 65 + o] = w1[(o * 64 + i) * 9 + 4];
            w2t[i * 65 + o] = w2[(o * 64 + i) * 9 + 4];
        }
    }
    if (tid == 0) normA_sh = normAG[b];
    __syncthreads();

    // slots: 0=A, 1=Z0 loaded.
    pass_single<1>(planes[0], planes[1], planes[2], tid);                     // Y0 = A@Z0 -> s2
    pass_single<0>(planes[1], planes[2], planes[0], tid);                     // W1 = .5(3I-Z0@Y0) -> s0
    pass_fused(planes[2], planes[0], planes[1], planes[3], planes[4], tid);   // Y1->s3, Z1->s4
    pass_single<0>(planes[4], planes[3], planes[1], tid);                     // W2 -> s1
    pass_fused(planes[3], planes[1], planes[4], planes[2], planes[0], tid);   // Y2->s2, Z2->s0
    pass_single<0>(planes[0], planes[2], planes[3], tid);                     // W3 -> s3
    pass_single<1>(planes[2], planes[3], planes[4], tid);                     // Y3 = Y2@W3 -> s4

    // Epilogue: r = 3u - Y3 (W3 (Z2 u)), u = colsum(Y3)
    colsum_stage(planes[4], uvec, part, tid);
    matvec_stage(planes[0], uvec, avec, part, tid);   // a = Z2 u
    matvec_stage(planes[3], avec, pvec, part, tid);   // p = W3 a
    matvec_stage(planes[4], pvec, wvec, part, tid);   // w = Y3 p

    if (tid < 64)
        ych[tid] = (3.0f * uvec[tid] - wvec[tid]) * (0.5f / 64.0f) * sqrtf(normA_sh);
    __syncthreads();
    if (tid < 64) {
        float t1 = b1[tid];
        for (int i = 0; i < 64; ++i) t1 += w1t[i * 65 + tid] * ych[i];
        hid[tid] = fmaxf(t1, 0.f);
    }
    __syncthreads();
    if (tid < 64) {
        float t2 = b2[tid];
        for (int i = 0; i < 64; ++i) t2 += w2t[i * 65 + tid] * hid[i];
        s_out[b * 64 + tid] = 1.0f / (1.0f + expf(-t2));
    }
}

// ---------------------------------------------------------------------------
// K3: out[b,c,h,w] = s[b,c] * x[b,c,h,w], float4 grid-stride
// ---------------------------------------------------------------------------
__global__ __launch_bounds__(256) void scale_kernel(const float* __restrict__ x,
                                                    const float* __restrict__ s,
                                                    float* __restrict__ out, int n4) {
    int idx = blockIdx.x * 256 + threadIdx.x;
    int stride = gridDim.x * 256;
    for (int f = idx; f < n4; f += stride) {
        float sv = s[f >> 10];
        float4 v = reinterpret_cast<const float4*>(x)[f];
        reinterpret_cast<float4*>(out)[f] = make_float4(v.x * sv, v.y * sv, v.z * sv, v.w * sv);
    }
}

extern "C" void kernel_launch(void* const* d_in, const int* in_sizes, int n_in,
                              void* d_out, int out_size, void* d_ws, size_t ws_size,
                              hipStream_t stream) {
    const float* x  = (const float*)d_in[0];
    const float* w1 = (const float*)d_in[1];
    const float* b1 = (const float*)d_in[2];
    const float* w2 = (const float*)d_in[3];
    const float* b2 = (const float*)d_in[4];
    float* out = (float*)d_out;
    float* ws  = (float*)d_ws;
    unsigned short* planesG = (unsigned short*)(ws + (size_t)256 * PART_STRIDE);
    float* normAG = (float*)(planesG + (size_t)16 * 4 * 4096);
    float* s_area = normAG + 16;

    cov_partial_kernel<<<dim3(256), dim3(256), 0, stream>>>(x, ws);
    reduce_convert_kernel<<<dim3(64), dim3(256), 0, stream>>>(ws, planesG, normAG);
    ns_kernel<<<dim3(16), dim3(1024), 0, stream>>>(planesG, normAG, w1, b1, w2, b2, s_area);
    scale_kernel<<<dim3(2048), dim3(256), 0, stream>>>(x, s_area, out, 1048576);
}